// Round 7
// baseline (270.401 us; speedup 1.0000x reference)
//
#include <hip/hip_runtime.h>

// ---------------- problem constants ----------------
constexpr int S    = 8192;
constexpr int D    = 768;
constexpr int NMID = 10;
constexpr int EPH  = 820;   // ceil(8192/10)

// adjacency: 10 row-clusters x 40 row-splits = 400 full-width items
constexpr int ADJ_SPLIT = 40;
constexpr int N_ADJ = 10 * ADJ_SPLIT;   // 400

// ---------------- workspace layout (float element offsets) ----------------
constexpr int PART_ADJ = 0;        // 400*10 = 4000
constexpr int PART_MID = 4096;     // 8*10*768 = 61440
constexpr int OFF_Y1   = 65536;    // 7680 (atomic, zeroed in K1)
constexpr int OFF_MATT = 73216;    // 7680
constexpr int OFF_SCB  = 80896;    // 128*20 softmax stats
constexpr int OFF_PVP  = 83456;    // 128*10*768 = 983040 PV partials

// ---------------- full-row adjacency item ----------------
// item = i*40 + s : rows [r0 + nr*s/40, r0 + nr*(s+1)/40) of row-cluster i,
// full 8192-wide coalesced read, col-cluster bucket reduce in LDS.
__device__ __forceinline__ void adj_item(const float* __restrict__ A,
                                         float* __restrict__ ws, int item) {
    __shared__ float bucket[2560];   // [10][256]
    __shared__ float red2[160];
    int i = item / ADJ_SPLIT, s = item % ADJ_SPLIT;
    int r0 = i * EPH, nr = min(EPH, S - r0);
    int rs0 = r0 + nr * s / ADJ_SPLIT, rs1 = r0 + nr * (s + 1) / ADJ_SPLIT;
    int tid = threadIdx.x;
    float acc[8];
#pragma unroll
    for (int u = 0; u < 8; ++u) acc[u] = 0.f;
    for (int r = rs0; r < rs1; ++r) {
        const float4* row = (const float4*)(A + (size_t)r * S);
#pragma unroll
        for (int u = 0; u < 8; ++u) {
            float4 v = row[tid + 256 * u];
            acc[u] += (v.x + v.y) + (v.z + v.w);
        }
    }
    for (int t = tid; t < 2560; t += 256) bucket[t] = 0.f;
    __syncthreads();
#pragma unroll
    for (int u = 0; u < 8; ++u) {
        int j = ((tid + 256 * u) * 4) / 820;
        bucket[j * 256 + tid] += acc[u];
    }
    __syncthreads();
    if (tid < 160) {
        int j = tid >> 4, seg = tid & 15;
        float sm = 0.f;
#pragma unroll
        for (int u = 0; u < 16; ++u) sm += bucket[j * 256 + seg * 16 + u];
        red2[tid] = sm;
    }
    __syncthreads();
    if (tid < 10) {
        float sm = 0.f;
#pragma unroll
        for (int g = 0; g < 16; ++g) sm += red2[tid * 16 + g];
        ws[PART_ADJ + item * 10 + tid] = sm;
    }
}

// mid column-sum partials: 10 cl x 3 cc x 8 sp = 240 items
__device__ __forceinline__ void mid_partial(const float* __restrict__ x,
                                            float* __restrict__ ws, int item) {
    int cl = item / 24, rem = item % 24;
    int cc = rem >> 3, sp = rem & 7;
    int r0 = cl * EPH, nr = min(EPH, S - r0);
    int rs0 = r0 + (nr * sp) / 8, rs1 = r0 + (nr * (sp + 1)) / 8;
    int c = cc * 256 + threadIdx.x;
    float acc = 0.f;
    for (int r = rs0; r < rs1; ++r) acc += x[(size_t)r * D + c];
    ws[PART_MID + (sp * NMID + cl) * D + c] = acc;
}

// out[NR][768] += mi[NR][16] @ W[kb:kb+16][768]  (atomic k-split)
template <int NR>
__device__ __forceinline__ void mm_core(const float* __restrict__ W,
                                        const float* mi,
                                        float* __restrict__ out, int kb) {
    int c = threadIdx.x;
    float a0[NR], a1[NR], a2[NR];
#pragma unroll
    for (int i = 0; i < NR; ++i) { a0[i] = 0.f; a1[i] = 0.f; a2[i] = 0.f; }
    for (int kk = 0; kk < 16; ++kk) {
        const float* wr = W + (size_t)(kb + kk) * D;
        float w0 = wr[c], w1 = wr[c + 256], w2 = wr[c + 512];
#pragma unroll
        for (int i = 0; i < NR; ++i) {
            float m = mi[i * 16 + kk];
            a0[i] += m * w0; a1[i] += m * w1; a2[i] += m * w2;
        }
    }
#pragma unroll
    for (int i = 0; i < NR; ++i) {
        atomicAdd(&out[i * D + c],       a0[i]);
        atomicAdd(&out[i * D + c + 256], a1[i]);
        atomicAdd(&out[i * D + c + 512], a2[i]);
    }
}

// full-K col-slice matmul: outS[i][c] = sum_k inL[i*768+k] * W[k][c0+c]
template <int NR>
__device__ __forceinline__ void fullk_slice(const float* __restrict__ W,
                                            const float* inL, float* red,
                                            float* outS, int c0) {
    int tid = threadIdx.x;
    int c = tid & 15, ks = tid >> 4;
    float acc[NR];
#pragma unroll
    for (int i = 0; i < NR; ++i) acc[i] = 0.f;
    int kb = ks * 48;
    for (int kk = 0; kk < 48; ++kk) {
        int k = kb + kk;
        float w = W[(size_t)k * D + c0 + c];
#pragma unroll
        for (int i = 0; i < NR; ++i) acc[i] += inL[i * D + k] * w;
    }
#pragma unroll
    for (int i = 0; i < NR; ++i) red[(ks * NR + i) * 16 + c] = acc[i];
    __syncthreads();
    if (tid < NR * 16) {
        int i = tid >> 4, cc = tid & 15;
        float s = 0.f;
#pragma unroll
        for (int k2 = 0; k2 < 16; ++k2) s += red[(k2 * NR + i) * 16 + cc];
        outS[i * 16 + cc] = s;
    }
    __syncthreads();
}

// ---- K1: mid partials (240) + adj items [0,260) + zero Y1 ----
__global__ __launch_bounds__(256) void k1(const float* __restrict__ A,
                                          const float* __restrict__ x,
                                          float* __restrict__ ws) {
    int bx = blockIdx.x;
    if (bx < 240) mid_partial(x, ws, bx);
    else if (bx < 500) adj_item(A, ws, bx - 240);
    else {
        int b = bx - 500;
        for (int t = b * 256 + threadIdx.x; t < 7680; t += 512)
            ws[OFF_Y1 + t] = 0.f;
    }
}

// ---- K2: MATT = mid @ attL (48) + adj items [260,330) ----
__global__ __launch_bounds__(256) void k2(const float* __restrict__ attL,
                                          const float* __restrict__ A,
                                          float* __restrict__ ws) {
    int bx = blockIdx.x, tid = threadIdx.x;
    if (bx >= 48) { adj_item(A, ws, 260 + bx - 48); return; }
    __shared__ float midL[7680];
    __shared__ float red[2560];
    __shared__ float outS[160];
    for (int t = tid; t < 7680; t += 256) {
        int cl = t / D, k = t - cl * D;
        float s = 0.f;
#pragma unroll
        for (int sp = 0; sp < 8; ++sp)
            s += ws[PART_MID + (sp * NMID + cl) * D + k];
        midL[t] = s;
    }
    __syncthreads();
    fullk_slice<10>(attL, midL, red, outS, bx * 16);
    if (tid < 160) ws[OFF_MATT + (tid >> 4) * D + bx * 16 + (tid & 15)] = outS[tid];
}

// ---- K3: scores + local stats + unnormalized PV partials (128 x 64 rows)
//          + adj items [330,400) ----
__global__ __launch_bounds__(256) void k3(const float* __restrict__ x,
                                          const float* __restrict__ A,
                                          float* __restrict__ ws) {
    int bx = blockIdx.x, tid = threadIdx.x;
    if (bx >= 128) { adj_item(A, ws, 330 + bx - 128); return; }
    __shared__ float ma[7680];
    __shared__ float sl[640];
    __shared__ float mloc[10];
    for (int t = tid; t < 7680; t += 256) ma[t] = ws[OFF_MATT + t];
    __syncthreads();
    const float4* maf = (const float4*)ma;
    const float4* x4  = (const float4*)x;
    int wave = tid >> 6, ln = tid & 63;
    int r0 = bx * 64;
    for (int rr = 0; rr < 16; ++rr) {
        int rl = wave * 16 + rr;
        int r = r0 + rl;
        float4 v0 = x4[(size_t)r * 192 + ln];
        float4 v1 = x4[(size_t)r * 192 + 64 + ln];
        float4 v2 = x4[(size_t)r * 192 + 128 + ln];
        int rc = r / EPH;
#pragma unroll
        for (int i = 0; i < NMID; ++i) {
            float4 m0 = maf[i * 192 + ln];
            float4 m1 = maf[i * 192 + 64 + ln];
            float4 m2 = maf[i * 192 + 128 + ln];
            float p = m0.x * v0.x + m0.y * v0.y + m0.z * v0.z + m0.w * v0.w
                    + m1.x * v1.x + m1.y * v1.y + m1.z * v1.z + m1.w * v1.w
                    + m2.x * v2.x + m2.y * v2.y + m2.z * v2.z + m2.w * v2.w;
#pragma unroll
            for (int off = 32; off > 0; off >>= 1) p += __shfl_down(p, off, 64);
            if (ln == 0) sl[rl * NMID + i] = (rc == i) ? 0.f : p;
        }
    }
    __syncthreads();
    if (tid < NMID) {
        float m = -1e30f;
        for (int r = 0; r < 64; ++r) m = fmaxf(m, sl[r * NMID + tid]);
        float s = 0.f;
        for (int r = 0; r < 64; ++r) s += expf(sl[r * NMID + tid] - m);
        mloc[tid] = m;
        ws[OFF_SCB + bx * 20 + tid * 2]     = m;
        ws[OFF_SCB + bx * 20 + tid * 2 + 1] = s;
    }
    __syncthreads();
    for (int t = tid; t < 640; t += 256) sl[t] = expf(sl[t] - mloc[t % NMID]);
    __syncthreads();
    float a0[NMID], a1[NMID], a2[NMID];
#pragma unroll
    for (int i = 0; i < NMID; ++i) { a0[i] = 0.f; a1[i] = 0.f; a2[i] = 0.f; }
    for (int r = 0; r < 64; ++r) {
        const float* xr = x + (size_t)(r0 + r) * D;
        float x0 = xr[tid], x1 = xr[tid + 256], x2 = xr[tid + 512];
#pragma unroll
        for (int i = 0; i < NMID; ++i) {
            float w = sl[r * NMID + i];
            a0[i] += w * x0; a1[i] += w * x1; a2[i] += w * x2;
        }
    }
#pragma unroll
    for (int i = 0; i < NMID; ++i) {
        float* base = ws + OFF_PVP + (bx * NMID + i) * D;
        base[tid]       = a0[i];
        base[tid + 256] = a1[i];
        base[tid + 512] = a2[i];
    }
}

// ---- K4: global softmax combine + inmid k-slice + Y1 += inmid@W1 (48) ----
__global__ __launch_bounds__(256) void k4(const float* __restrict__ W1,
                                          float* __restrict__ ws) {
    __shared__ float lm[160], ls[160], Mi[16], Zi[16];
    __shared__ float wts[1280];
    __shared__ float mi[160];
    int tid = threadIdx.x, kb = blockIdx.x * 16;
    if (tid < 160) {
        int i = tid >> 4, seg = tid & 15;
        float m = -1e30f;
        for (int b = seg * 8; b < seg * 8 + 8; ++b)
            m = fmaxf(m, ws[OFF_SCB + b * 20 + i * 2]);
        float s = 0.f;
        for (int b = seg * 8; b < seg * 8 + 8; ++b)
            s += ws[OFF_SCB + b * 20 + i * 2 + 1] *
                 expf(ws[OFF_SCB + b * 20 + i * 2] - m);
        lm[tid] = m; ls[tid] = s;
    }
    __syncthreads();
    if (tid < NMID) {
        float M = -1e30f;
        for (int g = 0; g < 16; ++g) M = fmaxf(M, lm[tid * 16 + g]);
        float Z = 0.f;
        for (int g = 0; g < 16; ++g) Z += ls[tid * 16 + g] * expf(lm[tid * 16 + g] - M);
        Mi[tid] = M; Zi[tid] = 1.f / Z;
    }
    __syncthreads();
    for (int t = tid; t < 1280; t += 256) {
        int b = t / NMID, i = t % NMID;
        wts[t] = expf(ws[OFF_SCB + b * 20 + i * 2] - Mi[i]) * Zi[i];
    }
    __syncthreads();
    if (tid < 160) {
        int i = tid >> 4, k = kb + (tid & 15);
        float s = 0.f;
#pragma unroll
        for (int sp = 0; sp < 8; ++sp)
            s += ws[PART_MID + (sp * NMID + i) * D + k];
        for (int b = 0; b < 128; ++b)
            s += wts[b * NMID + i] * ws[OFF_PVP + (b * NMID + i) * D + k];
        mi[tid] = s;
    }
    __syncthreads();
    mm_core<10>(W1, mi, ws + OFF_Y1, kb);
}

// ---- K5: aa/NM; XMID+MID2 full; Z2 full (redundant); s2/P2; out2;
//          Y2 col-slice; NH; out slice (48 blocks) ----
__global__ __launch_bounds__(256) void k5(const float* __restrict__ attH,
                                          const float* __restrict__ b1,
                                          const float* __restrict__ W2,
                                          const float* __restrict__ b2,
                                          float* __restrict__ ws,
                                          float* __restrict__ out) {
    __shared__ float xmidL[7680];
    __shared__ float mid2L[3840];
    __shared__ float z2L[3840];
    __shared__ float out2L[3840];
    __shared__ float red[1280];
    __shared__ float Y2s[80];
    __shared__ float aa[100], dg[16], NM[100];
    __shared__ float sred[200], s2l[64], P2[50];
    __shared__ float ha[32], dh[8], NH[32];
    int tid = threadIdx.x, kb = blockIdx.x * 16;

    if (tid < 100) {
        int i = tid / 10, j = tid % 10;
        float s = 0.f;
        for (int sp = 0; sp < ADJ_SPLIT; ++sp)
            s += ws[PART_ADJ + (i * ADJ_SPLIT + sp) * 10 + j];
        aa[tid] = s;
    }
    __syncthreads();
    if (tid < 10) {
        float s = 0.f;
#pragma unroll
        for (int j = 0; j < 10; ++j) s += (tid == j) ? 1.f : aa[tid * 10 + j];
        dg[tid] = 1.f / sqrtf(fmaxf(s, 1.f));
    }
    __syncthreads();
    if (tid < 100) {
        int i = tid / 10, j = tid % 10;
        NM[tid] = dg[i] * ((i == j) ? 1.f : aa[tid]) * dg[j];
    }
    __syncthreads();
    // XMID + MID2 (full, per block)
    for (int c = tid; c < D; c += 256) {
        float yv[10];
#pragma unroll
        for (int j = 0; j < 10; ++j) yv[j] = ws[OFF_Y1 + j * D + c];
        float bias = b1[c];
        float xm[10];
#pragma unroll
        for (int i = 0; i < 10; ++i) {
            float v = bias;
#pragma unroll
            for (int j = 0; j < 10; ++j) v += NM[i * 10 + j] * yv[j];
            xm[i] = fmaxf(v, 0.f);
            xmidL[i * D + c] = xm[i];
        }
#pragma unroll
        for (int a = 0; a < 5; ++a)
            mid2L[a * D + c] = xm[2 * a] + xm[2 * a + 1];
    }
    __syncthreads();
    // Z2 = mid2 @ attH, full, redundant per block
    for (int q = 0; q < 3; ++q) {
        int c = q * 256 + tid;
        float accz[5];
#pragma unroll
        for (int a = 0; a < 5; ++a) accz[a] = 0.f;
        for (int k = 0; k < D; ++k) {
            float w = attH[(size_t)k * D + c];
#pragma unroll
            for (int a = 0; a < 5; ++a) accz[a] += mid2L[a * D + k] * w;
        }
#pragma unroll
        for (int a = 0; a < 5; ++a) z2L[a * D + c] = accz[a];
    }
    __syncthreads();
    // s2 (masked) + softmax P2
    if (tid < 200) {
        int pp = tid >> 2, q = tid & 3;
        int i = pp / 10, r = pp % 10;
        float s = 0.f;
        for (int c = q * 192; c < q * 192 + 192; ++c)
            s += z2L[i * D + c] * xmidL[r * D + c];
        sred[tid] = s;
    }
    __syncthreads();
    if (tid < 50) {
        int i = tid / 10, r = tid % 10;
        float v = sred[tid * 4] + sred[tid * 4 + 1] + sred[tid * 4 + 2] + sred[tid * 4 + 3];
        s2l[tid] = ((r >> 1) == i) ? 0.f : v;
    }
    __syncthreads();
    if (tid < 5) {
        float mx = -1e30f;
#pragma unroll
        for (int r = 0; r < 10; ++r) mx = fmaxf(mx, s2l[tid * 10 + r]);
        float sm = 0.f; float e[10];
#pragma unroll
        for (int r = 0; r < 10; ++r) { e[r] = expf(s2l[tid * 10 + r] - mx); sm += e[r]; }
#pragma unroll
        for (int r = 0; r < 10; ++r) P2[tid * 10 + r] = e[r] / sm;
    }
    __syncthreads();
    // out2 = mid2 + P2 @ xmid (full)
    for (int t = tid; t < 3840; t += 256) {
        int i = t / D, k = t - i * D;
        float v = mid2L[t];
#pragma unroll
        for (int r = 0; r < 10; ++r) v += P2[i * 10 + r] * xmidL[r * D + k];
        out2L[t] = v;
    }
    __syncthreads();
    fullk_slice<5>(W2, out2L, red, Y2s, kb);
    if (tid < 25) {
        int a = tid / 5, b = tid % 5;
        ha[tid] = aa[(2 * a) * 10 + 2 * b] + aa[(2 * a) * 10 + 2 * b + 1]
                + aa[(2 * a + 1) * 10 + 2 * b] + aa[(2 * a + 1) * 10 + 2 * b + 1];
    }
    __syncthreads();
    if (tid < 5) {
        float s = 0.f;
#pragma unroll
        for (int j = 0; j < 5; ++j) s += (tid == j) ? 1.f : ha[tid * 5 + j];
        dh[tid] = 1.f / sqrtf(fmaxf(s, 1.f));
    }
    __syncthreads();
    if (tid < 25) {
        int i = tid / 5, j = tid % 5;
        NH[tid] = dh[i] * ((i == j) ? 1.f : ha[tid]) * dh[j];
    }
    __syncthreads();
    if (tid < 16) {
        int c = kb + tid;
        float bias = b2[c];
        float s = 0.f;
#pragma unroll
        for (int i = 0; i < 5; ++i) {
            float v = bias;
#pragma unroll
            for (int j = 0; j < 5; ++j) v += NH[i * 5 + j] * Y2s[j * 16 + tid];
            s += fmaxf(v, 0.f);
        }
        out[c] = s * 0.2f;
    }
}

// ---------------- launcher ----------------
extern "C" void kernel_launch(void* const* d_in, const int* in_sizes, int n_in,
                              void* d_out, int out_size, void* d_ws, size_t ws_size,
                              hipStream_t stream) {
    const float* x    = (const float*)d_in[0];
    const float* adj  = (const float*)d_in[1];
    const float* attL = (const float*)d_in[2];
    const float* W1   = (const float*)d_in[3];
    const float* b1   = (const float*)d_in[4];
    const float* attH = (const float*)d_in[5];
    const float* W2   = (const float*)d_in[6];
    const float* b2   = (const float*)d_in[7];
    float* ws  = (float*)d_ws;
    float* out = (float*)d_out;

    k1<<<502, 256, 0, stream>>>(adj, x, ws);
    k2<<<118, 256, 0, stream>>>(attL, adj, ws);
    k3<<<198, 256, 0, stream>>>(x, adj, ws);
    k4<<<48,  256, 0, stream>>>(W1, ws);
    k5<<<48,  256, 0, stream>>>(attH, b1, W2, b2, ws, out);
}

// Round 8
// 162.376 us; speedup vs baseline: 1.6653x; 1.6653x over previous
//
#include <hip/hip_runtime.h>

// ---------------- problem constants ----------------
constexpr int S    = 8192;
constexpr int D    = 768;
constexpr int NMID = 10;
constexpr int EPH  = 820;   // ceil(8192/10)

// adjacency: 10 row-clusters x 40 row-splits = 400 full-width items
constexpr int ADJ_SPLIT = 40;

// ---------------- workspace layout (float element offsets) ----------------
constexpr int PART_ADJ = 0;        // 400*10 = 4000
constexpr int PART_MID = 4096;     // 8*10*768 = 61440
constexpr int OFF_Y1   = 65536;    // 7680 (atomic, zeroed in K1)
constexpr int OFF_MATT = 73216;    // 7680
constexpr int OFF_XMID = 80896;    // 7680
constexpr int OFF_Z2   = 88576;    // 3840
constexpr int OFF_SCB  = 92416;    // 128*20 softmax stats
constexpr int OFF_PVP  = 95232;    // 128*10*768 = 983040 PV partials

// ---------------- full-row adjacency item ----------------
__device__ __forceinline__ void adj_item(const float* __restrict__ A,
                                         float* __restrict__ ws, int item) {
    __shared__ float bucket[2560];   // [10][256]
    __shared__ float red2[160];
    int i = item / ADJ_SPLIT, s = item % ADJ_SPLIT;
    int r0 = i * EPH, nr = min(EPH, S - r0);
    int rs0 = r0 + nr * s / ADJ_SPLIT, rs1 = r0 + nr * (s + 1) / ADJ_SPLIT;
    int tid = threadIdx.x;
    float acc[8];
#pragma unroll
    for (int u = 0; u < 8; ++u) acc[u] = 0.f;
    for (int r = rs0; r < rs1; ++r) {
        const float4* row = (const float4*)(A + (size_t)r * S);
#pragma unroll
        for (int u = 0; u < 8; ++u) {
            float4 v = row[tid + 256 * u];
            acc[u] += (v.x + v.y) + (v.z + v.w);
        }
    }
    for (int t = tid; t < 2560; t += 256) bucket[t] = 0.f;
    __syncthreads();
#pragma unroll
    for (int u = 0; u < 8; ++u) {
        int j = ((tid + 256 * u) * 4) / 820;
        bucket[j * 256 + tid] += acc[u];
    }
    __syncthreads();
    if (tid < 160) {
        int j = tid >> 4, seg = tid & 15;
        float sm = 0.f;
#pragma unroll
        for (int u = 0; u < 16; ++u) sm += bucket[j * 256 + seg * 16 + u];
        red2[tid] = sm;
    }
    __syncthreads();
    if (tid < 10) {
        float sm = 0.f;
#pragma unroll
        for (int g = 0; g < 16; ++g) sm += red2[tid * 16 + g];
        ws[PART_ADJ + item * 10 + tid] = sm;
    }
}

// mid column-sum partials: 10 cl x 3 cc x 8 sp = 240 items
__device__ __forceinline__ void mid_partial(const float* __restrict__ x,
                                            float* __restrict__ ws, int item) {
    int cl = item / 24, rem = item % 24;
    int cc = rem >> 3, sp = rem & 7;
    int r0 = cl * EPH, nr = min(EPH, S - r0);
    int rs0 = r0 + (nr * sp) / 8, rs1 = r0 + (nr * (sp + 1)) / 8;
    int c = cc * 256 + threadIdx.x;
    float acc = 0.f;
    for (int r = rs0; r < rs1; ++r) acc += x[(size_t)r * D + c];
    ws[PART_MID + (sp * NMID + cl) * D + c] = acc;
}

// out[NR][768] += mi[NR][16] @ W[kb:kb+16][768]  (atomic k-split)
template <int NR>
__device__ __forceinline__ void mm_core(const float* __restrict__ W,
                                        const float* mi,
                                        float* __restrict__ out, int kb) {
    int c = threadIdx.x;
    float a0[NR], a1[NR], a2[NR];
#pragma unroll
    for (int i = 0; i < NR; ++i) { a0[i] = 0.f; a1[i] = 0.f; a2[i] = 0.f; }
    for (int kk = 0; kk < 16; ++kk) {
        const float* wr = W + (size_t)(kb + kk) * D;
        float w0 = wr[c], w1 = wr[c + 256], w2 = wr[c + 512];
#pragma unroll
        for (int i = 0; i < NR; ++i) {
            float m = mi[i * 16 + kk];
            a0[i] += m * w0; a1[i] += m * w1; a2[i] += m * w2;
        }
    }
#pragma unroll
    for (int i = 0; i < NR; ++i) {
        atomicAdd(&out[i * D + c],       a0[i]);
        atomicAdd(&out[i * D + c + 256], a1[i]);
        atomicAdd(&out[i * D + c + 512], a2[i]);
    }
}

// full-K col-slice matmul: outS[i][c] = sum_k inL[i*768+k] * W[k][c0+c]
template <int NR>
__device__ __forceinline__ void fullk_slice(const float* __restrict__ W,
                                            const float* inL, float* red,
                                            float* outS, int c0) {
    int tid = threadIdx.x;
    int c = tid & 15, ks = tid >> 4;
    float acc[NR];
#pragma unroll
    for (int i = 0; i < NR; ++i) acc[i] = 0.f;
    int kb = ks * 48;
    for (int kk = 0; kk < 48; ++kk) {
        int k = kb + kk;
        float w = W[(size_t)k * D + c0 + c];
#pragma unroll
        for (int i = 0; i < NR; ++i) acc[i] += inL[i * D + k] * w;
    }
#pragma unroll
    for (int i = 0; i < NR; ++i) red[(ks * NR + i) * 16 + c] = acc[i];
    __syncthreads();
    if (tid < NR * 16) {
        int i = tid >> 4, cc = tid & 15;
        float s = 0.f;
#pragma unroll
        for (int k2 = 0; k2 < 16; ++k2) s += red[(k2 * NR + i) * 16 + cc];
        outS[i * 16 + cc] = s;
    }
    __syncthreads();
}

// ---- K1: mid partials (240) + adj items [0,260) + zero Y1 ----
__global__ __launch_bounds__(256) void k1(const float* __restrict__ A,
                                          const float* __restrict__ x,
                                          float* __restrict__ ws) {
    int bx = blockIdx.x;
    if (bx < 240) mid_partial(x, ws, bx);
    else if (bx < 500) adj_item(A, ws, bx - 240);
    else {
        int b = bx - 500;
        for (int t = b * 256 + threadIdx.x; t < 7680; t += 512)
            ws[OFF_Y1 + t] = 0.f;
    }
}

// ---- K2: MATT = mid @ attL (48) + adj items [260,330) ----
__global__ __launch_bounds__(256) void k2(const float* __restrict__ attL,
                                          const float* __restrict__ A,
                                          float* __restrict__ ws) {
    int bx = blockIdx.x, tid = threadIdx.x;
    if (bx >= 48) { adj_item(A, ws, 260 + bx - 48); return; }
    __shared__ float midL[7680];
    __shared__ float red[2560];
    __shared__ float outS[160];
    for (int t = tid; t < 7680; t += 256) {
        int cl = t / D, k = t - cl * D;
        float s = 0.f;
#pragma unroll
        for (int sp = 0; sp < 8; ++sp)
            s += ws[PART_MID + (sp * NMID + cl) * D + k];
        midL[t] = s;
    }
    __syncthreads();
    fullk_slice<10>(attL, midL, red, outS, bx * 16);
    if (tid < 160) ws[OFF_MATT + (tid >> 4) * D + bx * 16 + (tid & 15)] = outS[tid];
}

// ---- K3: scores + local stats + unnormalized PV partials (128 x 64 rows)
//          + adj items [330,400) ----
__global__ __launch_bounds__(256) void k3(const float* __restrict__ x,
                                          const float* __restrict__ A,
                                          float* __restrict__ ws) {
    int bx = blockIdx.x, tid = threadIdx.x;
    if (bx >= 128) { adj_item(A, ws, 330 + bx - 128); return; }
    __shared__ float ma[7680];
    __shared__ float sl[640];
    __shared__ float mloc[10];
    for (int t = tid; t < 7680; t += 256) ma[t] = ws[OFF_MATT + t];
    __syncthreads();
    const float4* maf = (const float4*)ma;
    const float4* x4  = (const float4*)x;
    int wave = tid >> 6, ln = tid & 63;
    int r0 = bx * 64;
    for (int rr = 0; rr < 16; ++rr) {
        int rl = wave * 16 + rr;
        int r = r0 + rl;
        float4 v0 = x4[(size_t)r * 192 + ln];
        float4 v1 = x4[(size_t)r * 192 + 64 + ln];
        float4 v2 = x4[(size_t)r * 192 + 128 + ln];
        int rc = r / EPH;
#pragma unroll
        for (int i = 0; i < NMID; ++i) {
            float4 m0 = maf[i * 192 + ln];
            float4 m1 = maf[i * 192 + 64 + ln];
            float4 m2 = maf[i * 192 + 128 + ln];
            float p = m0.x * v0.x + m0.y * v0.y + m0.z * v0.z + m0.w * v0.w
                    + m1.x * v1.x + m1.y * v1.y + m1.z * v1.z + m1.w * v1.w
                    + m2.x * v2.x + m2.y * v2.y + m2.z * v2.z + m2.w * v2.w;
#pragma unroll
            for (int off = 32; off > 0; off >>= 1) p += __shfl_down(p, off, 64);
            if (ln == 0) sl[rl * NMID + i] = (rc == i) ? 0.f : p;
        }
    }
    __syncthreads();
    if (tid < NMID) {
        float m = -1e30f;
        for (int r = 0; r < 64; ++r) m = fmaxf(m, sl[r * NMID + tid]);
        float s = 0.f;
        for (int r = 0; r < 64; ++r) s += expf(sl[r * NMID + tid] - m);
        mloc[tid] = m;
        ws[OFF_SCB + bx * 20 + tid * 2]     = m;
        ws[OFF_SCB + bx * 20 + tid * 2 + 1] = s;
    }
    __syncthreads();
    for (int t = tid; t < 640; t += 256) sl[t] = expf(sl[t] - mloc[t % NMID]);
    __syncthreads();
    float a0[NMID], a1[NMID], a2[NMID];
#pragma unroll
    for (int i = 0; i < NMID; ++i) { a0[i] = 0.f; a1[i] = 0.f; a2[i] = 0.f; }
    for (int r = 0; r < 64; ++r) {
        const float* xr = x + (size_t)(r0 + r) * D;
        float x0 = xr[tid], x1 = xr[tid + 256], x2 = xr[tid + 512];
#pragma unroll
        for (int i = 0; i < NMID; ++i) {
            float w = sl[r * NMID + i];
            a0[i] += w * x0; a1[i] += w * x1; a2[i] += w * x2;
        }
    }
#pragma unroll
    for (int i = 0; i < NMID; ++i) {
        float* base = ws + OFF_PVP + (bx * NMID + i) * D;
        base[tid]       = a0[i];
        base[tid + 256] = a1[i];
        base[tid + 512] = a2[i];
    }
}

// ---- K4: global softmax combine + inmid k-slice + Y1 += inmid@W1 (48) ----
__global__ __launch_bounds__(256) void k4(const float* __restrict__ W1,
                                          float* __restrict__ ws) {
    __shared__ float lm[160], ls[160], Mi[16], Zi[16];
    __shared__ float wts[1280];
    __shared__ float mi[160];
    int tid = threadIdx.x, kb = blockIdx.x * 16;
    if (tid < 160) {
        int i = tid >> 4, seg = tid & 15;
        float m = -1e30f;
        for (int b = seg * 8; b < seg * 8 + 8; ++b)
            m = fmaxf(m, ws[OFF_SCB + b * 20 + i * 2]);
        float s = 0.f;
        for (int b = seg * 8; b < seg * 8 + 8; ++b)
            s += ws[OFF_SCB + b * 20 + i * 2 + 1] *
                 expf(ws[OFF_SCB + b * 20 + i * 2] - m);
        lm[tid] = m; ls[tid] = s;
    }
    __syncthreads();
    if (tid < NMID) {
        float M = -1e30f;
        for (int g = 0; g < 16; ++g) M = fmaxf(M, lm[tid * 16 + g]);
        float Z = 0.f;
        for (int g = 0; g < 16; ++g) Z += ls[tid * 16 + g] * expf(lm[tid * 16 + g] - M);
        Mi[tid] = M; Zi[tid] = 1.f / Z;
    }
    __syncthreads();
    for (int t = tid; t < 1280; t += 256) {
        int b = t / NMID, i = t % NMID;
        wts[t] = expf(ws[OFF_SCB + b * 20 + i * 2] - Mi[i]) * Zi[i];
    }
    __syncthreads();
    if (tid < 160) {
        int i = tid >> 4, k = kb + (tid & 15);
        float s = 0.f;
#pragma unroll
        for (int sp = 0; sp < 8; ++sp)
            s += ws[PART_MID + (sp * NMID + i) * D + k];
        for (int b = 0; b < 128; ++b)
            s += wts[b * NMID + i] * ws[OFF_PVP + (b * NMID + i) * D + k];
        mi[tid] = s;
    }
    __syncthreads();
    mm_core<10>(W1, mi, ws + OFF_Y1, kb);
}

// ---- K5: aa/NM; full XMID+mid2 in LDS; write XMID slice; Z2 slice (48) ----
__global__ __launch_bounds__(256) void k5(const float* __restrict__ attH,
                                          const float* __restrict__ b1,
                                          float* __restrict__ ws) {
    __shared__ float xmidL[7680];
    __shared__ float mid2L[3840];
    __shared__ float red[1280];
    __shared__ float z2s[80];
    __shared__ float aa[100], dg[16], NM[100];
    int tid = threadIdx.x, kb = blockIdx.x * 16;

    if (tid < 100) {
        int i = tid / 10, j = tid % 10;
        float s = 0.f;
        for (int sp = 0; sp < ADJ_SPLIT; ++sp)
            s += ws[PART_ADJ + (i * ADJ_SPLIT + sp) * 10 + j];
        aa[tid] = s;
    }
    __syncthreads();
    if (tid < 10) {
        float s = 0.f;
#pragma unroll
        for (int j = 0; j < 10; ++j) s += (tid == j) ? 1.f : aa[tid * 10 + j];
        dg[tid] = 1.f / sqrtf(fmaxf(s, 1.f));
    }
    __syncthreads();
    if (tid < 100) {
        int i = tid / 10, j = tid % 10;
        NM[tid] = dg[i] * ((i == j) ? 1.f : aa[tid]) * dg[j];
    }
    __syncthreads();
    // XMID + mid2 full (per block, cheap VALU on L2-resident Y1)
    for (int c = tid; c < D; c += 256) {
        float yv[10];
#pragma unroll
        for (int j = 0; j < 10; ++j) yv[j] = ws[OFF_Y1 + j * D + c];
        float bias = b1[c];
        float xm[10];
#pragma unroll
        for (int i = 0; i < 10; ++i) {
            float v = bias;
#pragma unroll
            for (int j = 0; j < 10; ++j) v += NM[i * 10 + j] * yv[j];
            xm[i] = fmaxf(v, 0.f);
            xmidL[i * D + c] = xm[i];
        }
#pragma unroll
        for (int a = 0; a < 5; ++a)
            mid2L[a * D + c] = xm[2 * a] + xm[2 * a + 1];
    }
    __syncthreads();
    // write this block's 16-col slice of XMID
    if (tid < 160) {
        int i = tid >> 4, cc = tid & 15;
        ws[OFF_XMID + i * D + kb + cc] = xmidL[i * D + kb + cc];
    }
    // Z2 slice: only 16 columns of attH read per block
    fullk_slice<5>(attH, mid2L, red, z2s, kb);
    if (tid < 80) ws[OFF_Z2 + (tid >> 4) * D + kb + (tid & 15)] = z2s[tid];
}

// ---- K6: s2/P2; out2 (mid2 derived); Y2 slice; NH; out slice (48) ----
__global__ __launch_bounds__(256) void k6(const float* __restrict__ W2,
                                          const float* __restrict__ b2,
                                          float* __restrict__ ws,
                                          float* __restrict__ out) {
    __shared__ float xmidL[7680];
    __shared__ float out2L[3840];
    __shared__ float red[1280];
    __shared__ float Y2s[80];
    __shared__ float sred[200], s2l[64], P2[50];
    __shared__ float aa[100], ha[32], dh[8], NH[32];
    int tid = threadIdx.x, kb = blockIdx.x * 16;

    for (int t = tid; t < 7680; t += 256) xmidL[t] = ws[OFF_XMID + t];
    if (tid >= 56 && tid < 156) {
        int t2 = tid - 56;
        int i = t2 / 10, j = t2 % 10;
        float s = 0.f;
        for (int sp = 0; sp < ADJ_SPLIT; ++sp)
            s += ws[PART_ADJ + (i * ADJ_SPLIT + sp) * 10 + j];
        aa[t2] = s;
    }
    __syncthreads();
    if (tid < 200) {
        int pp = tid >> 2, q = tid & 3;
        int i = pp / 10, r = pp % 10;
        const float* z = ws + OFF_Z2 + i * D;
        float s = 0.f;
        for (int c = q * 192; c < q * 192 + 192; ++c)
            s += z[c] * xmidL[r * D + c];
        sred[tid] = s;
    }
    __syncthreads();
    if (tid < 50) {
        int i = tid / 10, r = tid % 10;
        float v = sred[tid * 4] + sred[tid * 4 + 1] + sred[tid * 4 + 2] + sred[tid * 4 + 3];
        s2l[tid] = ((r >> 1) == i) ? 0.f : v;
    }
    __syncthreads();
    if (tid < 5) {
        float mx = -1e30f;
#pragma unroll
        for (int r = 0; r < 10; ++r) mx = fmaxf(mx, s2l[tid * 10 + r]);
        float sm = 0.f; float e[10];
#pragma unroll
        for (int r = 0; r < 10; ++r) { e[r] = expf(s2l[tid * 10 + r] - mx); sm += e[r]; }
#pragma unroll
        for (int r = 0; r < 10; ++r) P2[tid * 10 + r] = e[r] / sm;
    }
    __syncthreads();
    // out2 = mid2 + P2 @ xmid, mid2 derived from xmid pair-sums
    for (int t = tid; t < 3840; t += 256) {
        int i = t / D, k = t - i * D;
        float v = xmidL[(2 * i) * D + k] + xmidL[(2 * i + 1) * D + k];
#pragma unroll
        for (int r = 0; r < 10; ++r) v += P2[i * 10 + r] * xmidL[r * D + k];
        out2L[t] = v;
    }
    __syncthreads();
    fullk_slice<5>(W2, out2L, red, Y2s, kb);
    if (tid < 25) {
        int a = tid / 5, b = tid % 5;
        ha[tid] = aa[(2 * a) * 10 + 2 * b] + aa[(2 * a) * 10 + 2 * b + 1]
                + aa[(2 * a + 1) * 10 + 2 * b] + aa[(2 * a + 1) * 10 + 2 * b + 1];
    }
    __syncthreads();
    if (tid < 5) {
        float s = 0.f;
#pragma unroll
        for (int j = 0; j < 5; ++j) s += (tid == j) ? 1.f : ha[tid * 5 + j];
        dh[tid] = 1.f / sqrtf(fmaxf(s, 1.f));
    }
    __syncthreads();
    if (tid < 25) {
        int i = tid / 5, j = tid % 5;
        NH[tid] = dh[i] * ((i == j) ? 1.f : ha[tid]) * dh[j];
    }
    __syncthreads();
    if (tid < 16) {
        int c = kb + tid;
        float bias = b2[c];
        float s = 0.f;
#pragma unroll
        for (int i = 0; i < 5; ++i) {
            float v = bias;
#pragma unroll
            for (int j = 0; j < 5; ++j) v += NH[i * 5 + j] * Y2s[j * 16 + tid];
            s += fmaxf(v, 0.f);
        }
        out[c] = s * 0.2f;
    }
}

// ---------------- launcher ----------------
extern "C" void kernel_launch(void* const* d_in, const int* in_sizes, int n_in,
                              void* d_out, int out_size, void* d_ws, size_t ws_size,
                              hipStream_t stream) {
    const float* x    = (const float*)d_in[0];
    const float* adj  = (const float*)d_in[1];
    const float* attL = (const float*)d_in[2];
    const float* W1   = (const float*)d_in[3];
    const float* b1   = (const float*)d_in[4];
    const float* attH = (const float*)d_in[5];
    const float* W2   = (const float*)d_in[6];
    const float* b2   = (const float*)d_in[7];
    float* ws  = (float*)d_ws;
    float* out = (float*)d_out;

    k1<<<502, 256, 0, stream>>>(adj, x, ws);
    k2<<<118, 256, 0, stream>>>(attL, adj, ws);
    k3<<<198, 256, 0, stream>>>(x, adj, ws);
    k4<<<48,  256, 0, stream>>>(W1, ws);
    k5<<<48,  256, 0, stream>>>(attH, b1, ws);
    k6<<<48,  256, 0, stream>>>(W2, b2, ws, out);
}